// Round 16
// baseline (281.826 us; speedup 1.0000x reference)
//
#include <hip/hip_runtime.h>
#include <math.h>

// Problem constants (match reference setup_inputs()).
#define NNODES 10000
#define MPAD   10112           // 79 * 128 (MFMA M-tile padding)
#define NEDGES 80000           // directed edges before self loops
#define ETOT   (NEDGES + NNODES)

typedef __attribute__((ext_vector_type(4))) float f32x4;
typedef __attribute__((ext_vector_type(8))) short bf16x8;
typedef __attribute__((ext_vector_type(4))) unsigned int u32x4;

__device__ inline unsigned short f2bf(float f) {
    unsigned int u = __float_as_uint(f);
    unsigned int r = (u + 0x7fffu + ((u >> 16) & 1u)) >> 16;
    return (unsigned short)r;
}
__device__ inline float bf2f(unsigned short h) {
    return __uint_as_float(((unsigned int)h) << 16);
}
__device__ inline float lrelu01(float v) { return (v > 0.f) ? v : 0.1f * v; }
__device__ inline float lrelu02(float v) { return (v > 0.f) ? v : 0.2f * v; }

// ---------------------------------------------------------------------------
// Mega prep kernel: count_deg | x->bf16 convert | make_wsd | 3 transposes.
// ---------------------------------------------------------------------------
__global__ __launch_bounds__(256) void prep_all(const int* __restrict__ ei,
                                                int* __restrict__ indeg,
                                                const float* __restrict__ x,
                                                unsigned short* __restrict__ xb,
                                                const float* __restrict__ W1,
                                                const float* __restrict__ as1,
                                                const float* __restrict__ ad1,
                                                float* __restrict__ wsrc,
                                                float* __restrict__ wdst,
                                                const float* __restrict__ W2,
                                                const float* __restrict__ W3,
                                                unsigned short* __restrict__ W1t,
                                                unsigned short* __restrict__ W2t,
                                                unsigned short* __restrict__ W3t) {
    __shared__ float t[32][33];
    int b = blockIdx.x, tid = threadIdx.x;
    if (b < 352) {                       // count_deg
        int i = b * 256 + tid;
        if (i < ETOT) {
            int dst = (i < NEDGES) ? ei[NEDGES + i] : (i - NEDGES);
            atomicAdd(&indeg[dst], 1);
        }
        return;
    }
    b -= 352;
    if (b < 5000) {                      // convert x -> bf16
        int i = b * 256 + tid;
        if (i < NNODES * 128) xb[i] = f2bf(x[i]);
        return;
    }
    b -= 5000;
    if (b < 5) {                         // make_wsd: wsrc/wdst [10][128]
        int idx = b * 256 + tid;
        if (idx < 1280) {
            int h = idx >> 7, k = idx & 127;
            const float* wrow = W1 + (size_t)k * 2560 + h * 256;
            const float* as = as1 + h * 256;
            const float* ad = ad1 + h * 256;
            float s = 0.f, d = 0.f;
            for (int c = 0; c < 256; c += 4) {
                f32x4 w = *(const f32x4*)&wrow[c];
                f32x4 a = *(const f32x4*)&as[c];
                f32x4 bb = *(const f32x4*)&ad[c];
                #pragma unroll
                for (int j = 0; j < 4; ++j) { s += w[j] * a[j]; d += w[j] * bb[j]; }
            }
            wsrc[h * 128 + k] = s;
            wdst[h * 128 + k] = d;
        }
        return;
    }
    b -= 5;                              // transposes (1496 32x32 tiles)
    const float* W; unsigned short* Wt; int K, N, nb, kb;
    if (b < 320)       { W = W1; Wt = W1t; K = 128;  N = 2560; nb = b % 80; kb = b / 80; }
    else if (b < 1440) { W = W2; Wt = W2t; K = 2560; N = 448;  int i = b - 320;  nb = i % 14; kb = i / 14; }
    else               { W = W3; Wt = W3t; K = 448;  N = 128;  int i = b - 1440; nb = i % 4;  kb = i / 4;  }
    int kb32 = kb * 32, nb32 = nb * 32;
    int tx = tid & 31, ty = tid >> 5;    // 32 x 8
    #pragma unroll
    for (int i = 0; i < 32; i += 8)
        t[ty + i][tx] = W[(size_t)(kb32 + ty + i) * N + nb32 + tx];
    __syncthreads();
    #pragma unroll
    for (int i = 0; i < 32; i += 8)
        Wt[(size_t)(nb32 + ty + i) * K + kb32 + tx] = f2bf(t[tx][ty + i]);
}

// ---------------------------------------------------------------------------
// Single-block exclusive scan over indeg -> row_ptr (and cursor copy).
// ---------------------------------------------------------------------------
__global__ void scan_rowptr(const int* __restrict__ indeg, int* __restrict__ row_ptr,
                            int* __restrict__ cursor, int n) {
    __shared__ int sums[1024];
    int tid = threadIdx.x;
    int per = (n + 1023) / 1024;
    int start = tid * per;
    int end = start + per; if (end > n) end = n;
    int s = 0;
    for (int i = start; i < end; ++i) s += indeg[i];
    sums[tid] = s;
    __syncthreads();
    for (int off = 1; off < 1024; off <<= 1) {
        int v = (tid >= off) ? sums[tid - off] : 0;
        __syncthreads();
        sums[tid] += v;
        __syncthreads();
    }
    int excl = (tid == 0) ? 0 : sums[tid - 1];
    for (int i = start; i < end; ++i) {
        row_ptr[i] = excl;
        cursor[i]  = excl;
        excl += indeg[i];
    }
    if (tid == 1023) row_ptr[n] = sums[1023];
}

// ---------------------------------------------------------------------------
// scatter_edges | e1_dots merged. Blocks [0,352) scatter, [352,2852) e1.
// ---------------------------------------------------------------------------
__global__ __launch_bounds__(256) void scatter_e1(const int* __restrict__ ei,
                                                  int* __restrict__ cursor,
                                                  int* __restrict__ col,
                                                  const unsigned short* __restrict__ xb,
                                                  const float* __restrict__ wsrc,
                                                  const float* __restrict__ wdst,
                                                  float* __restrict__ e_src,
                                                  float* __restrict__ e_dst) {
    __shared__ float ws[1280], wd[1280];
    int b = blockIdx.x, tid = threadIdx.x;
    if (b < 352) {
        int i = b * 256 + tid;
        if (i < ETOT) {
            int src, dst;
            if (i < NEDGES) { src = ei[i]; dst = ei[NEDGES + i]; }
            else            { src = i - NEDGES; dst = i - NEDGES; }
            int pos = atomicAdd(&cursor[dst], 1);
            col[pos] = src;
        }
        return;
    }
    b -= 352;
    for (int i = tid; i < 1280; i += 256) { ws[i] = wsrc[i]; wd[i] = wdst[i]; }
    __syncthreads();
    int node = b * 4 + (tid >> 6);
    int lane = tid & 63;
    if (node >= NNODES) return;
    unsigned int xv = ((const unsigned int*)xb)[node * 64 + lane];
    float v0 = bf2f((unsigned short)(xv & 0xffffu));
    float v1 = bf2f((unsigned short)(xv >> 16));
    #pragma unroll
    for (int h = 0; h < 10; ++h) {
        float ps = v0 * ws[h * 128 + 2 * lane] + v1 * ws[h * 128 + 2 * lane + 1];
        float pd = v0 * wd[h * 128 + 2 * lane] + v1 * wd[h * 128 + 2 * lane + 1];
        #pragma unroll
        for (int off = 32; off; off >>= 1) {
            ps += __shfl_down(ps, off);
            pd += __shfl_down(pd, off);
        }
        if (lane == 0) { e_src[node * 10 + h] = ps; e_dst[node * 10 + h] = pd; }
    }
}

// ---------------------------------------------------------------------------
// Layer-1 x-aggregation: xagg[d,h,:] = sum_s alpha[d,s,h] * x[s,:].
// ---------------------------------------------------------------------------
__global__ __launch_bounds__(64) void agg_x(const unsigned short* __restrict__ xb,
                                            const float* __restrict__ e_src,
                                            const float* __restrict__ e_dst,
                                            const int* __restrict__ row_ptr,
                                            const int* __restrict__ col,
                                            unsigned short* __restrict__ xagg) {
    int node = blockIdx.x;
    int lane = threadIdx.x;
    int rs = row_ptr[node], re = row_ptr[node + 1];
    float edv = (lane < 10) ? e_dst[node * 10 + lane] : 0.f;

    float dn = 0.f;
    float a0[10], a1[10];
    #pragma unroll
    for (int h = 0; h < 10; ++h) { a0[h] = 0.f; a1[h] = 0.f; }
    for (int i = rs; i < re; ++i) {
        int s = col[i];
        float w = 0.f;
        if (lane < 10) w = __expf(lrelu02(e_src[s * 10 + lane] + edv));
        dn += w;
        unsigned int xv = ((const unsigned int*)xb)[s * 64 + lane];
        float v0 = bf2f((unsigned short)(xv & 0xffffu));
        float v1 = bf2f((unsigned short)(xv >> 16));
        #pragma unroll
        for (int h = 0; h < 10; ++h) {
            float wh = __shfl(w, h);
            a0[h] += wh * v0;
            a1[h] += wh * v1;
        }
    }
    #pragma unroll
    for (int h = 0; h < 10; ++h) {
        float rdn = 1.f / (__shfl(dn, h) + 1e-16f);
        unsigned int o = (unsigned int)f2bf(a0[h] * rdn) |
                         ((unsigned int)f2bf(a1[h] * rdn) << 16);
        ((unsigned int*)xagg)[((size_t)node * 10 + h) * 64 + lane] = o;
    }
}

// ---------------------------------------------------------------------------
// GBK=64 LDS XOR-8 swizzle: LDS chunk position p of row R holds global
// 16B-chunk p^(R&7); staging lane fetches (l&7)^(l>>3); reads un-permute
// with q^(row16&7) -> 2-way aliasing = free.
// ---------------------------------------------------------------------------

// Layer-1 batched per-head GEMM (K=128, GBK=64): x2 = lrelu01(xagg@W1t + b1).
#define GBM 128
__global__ __launch_bounds__(256) void gemm_l1(const unsigned short* __restrict__ A,
                                               const unsigned short* __restrict__ Bt,
                                               const float* __restrict__ bias,
                                               unsigned short* __restrict__ C) {
    constexpr int NT = 128, NI = 4, K = 128;
    __shared__ short As[GBM * 64];
    __shared__ short Bs[NT * 64];
    int h  = blockIdx.x >> 1;
    int nt = blockIdx.x & 1;
    int bn = h * 256 + nt * 128;
    int bm = blockIdx.y * GBM;
    int tid  = threadIdx.x;
    int wave = tid >> 6, lane = tid & 63;
    int wr = wave >> 1, wc = wave & 1;
    int lr8    = lane >> 3;
    int gchunk = (lane & 7) ^ lr8;
    int row16  = lane & 15;
    int quad   = lane >> 4;

    f32x4 acc[4][NI];
    #pragma unroll
    for (int mi = 0; mi < 4; ++mi)
        #pragma unroll
        for (int ni = 0; ni < NI; ++ni) acc[mi][ni] = (f32x4){0.f, 0.f, 0.f, 0.f};

    for (int k0 = 0; k0 < K; k0 += 64) {
        #pragma unroll
        for (int r = 0; r < 4; ++r) {
            int cs = r * 4 + wave;
            int row = cs * 8 + lr8;
            const unsigned short* gp = A + ((size_t)(bm + row) * 10 + h) * K + k0 + gchunk * 8;
            __builtin_amdgcn_global_load_lds(
                (const __attribute__((address_space(1))) void*)gp,
                (__attribute__((address_space(3))) void*)&As[cs * 512], 16, 0, 0);
        }
        #pragma unroll
        for (int r = 0; r < 4; ++r) {
            int cs = r * 4 + wave;
            int row = cs * 8 + lr8;
            const unsigned short* gp = Bt + (size_t)(bn + row) * K + k0 + gchunk * 8;
            __builtin_amdgcn_global_load_lds(
                (const __attribute__((address_space(1))) void*)gp,
                (__attribute__((address_space(3))) void*)&Bs[cs * 512], 16, 0, 0);
        }
        __syncthreads();
        #pragma unroll
        for (int kh = 0; kh < 2; ++kh) {
            int q = kh * 4 + quad;
            int pos = (q ^ (row16 & 7)) * 8;
            bf16x8 af[4], bfr[NI];
            #pragma unroll
            for (int mi = 0; mi < 4; ++mi)
                af[mi] = *(const bf16x8*)&As[(wr * 64 + mi * 16 + row16) * 64 + pos];
            #pragma unroll
            for (int ni = 0; ni < NI; ++ni)
                bfr[ni] = *(const bf16x8*)&Bs[(wc * 64 + ni * 16 + row16) * 64 + pos];
            #pragma unroll
            for (int mi = 0; mi < 4; ++mi)
                #pragma unroll
                for (int ni = 0; ni < NI; ++ni)
                    acc[mi][ni] = __builtin_amdgcn_mfma_f32_16x16x32_bf16(
                        af[mi], bfr[ni], acc[mi][ni], 0, 0, 0);
        }
        __syncthreads();
    }

    int rbase = bm + wr * 64 + (lane >> 4) * 4;
    #pragma unroll
    for (int mi = 0; mi < 4; ++mi)
        #pragma unroll
        for (int ni = 0; ni < NI; ++ni) {
            int cc = bn + wc * 64 + ni * 16 + (lane & 15);
            float b = bias[cc];
            #pragma unroll
            for (int r = 0; r < 4; ++r) {
                float v = lrelu01(acc[mi][ni][r] + b);
                C[(size_t)(rbase + mi * 16 + r) * 2560 + cc] = f2bf(v);
            }
        }
}

// ---------------------------------------------------------------------------
// GBK=64 GEMM, XCD-swizzled grid.x + split-K grid.y (bf16 partials).
// kend clamped to K so uneven splits work (e.g. K=448 -> 256+192).
// ---------------------------------------------------------------------------
template <int NT>
__global__ __launch_bounds__(256) void gemm_k64(const unsigned short* __restrict__ A,
                                                const unsigned short* __restrict__ Bt,
                                                unsigned short* __restrict__ C,
                                                int N, int nbn, int K, int klen) {
    constexpr int NI = NT / 32;
    __shared__ short As[GBM * 64];
    __shared__ short Bs[NT * 64];
    int b = blockIdx.x;
    int x = b & 7, t = b >> 3;
    int j = x + 8 * (t / nbn);
    if (j >= MPAD / GBM) return;
    int bn = (t % nbn) * NT;
    int bm = j * GBM;
    int kbeg = blockIdx.y * klen;
    int kend = kbeg + klen; if (kend > K) kend = K;
    size_t zoff = (size_t)blockIdx.y * MPAD * N;
    int tid  = threadIdx.x;
    int wave = tid >> 6, lane = tid & 63;
    int wr = wave >> 1, wc = wave & 1;
    int lr8    = lane >> 3;
    int gchunk = (lane & 7) ^ lr8;
    int row16  = lane & 15;
    int quad   = lane >> 4;

    f32x4 acc[4][NI];
    #pragma unroll
    for (int mi = 0; mi < 4; ++mi)
        #pragma unroll
        for (int ni = 0; ni < NI; ++ni) acc[mi][ni] = (f32x4){0.f, 0.f, 0.f, 0.f};

    for (int k0 = kbeg; k0 < kend; k0 += 64) {
        #pragma unroll
        for (int r = 0; r < 4; ++r) {
            int cs = r * 4 + wave;
            int row = cs * 8 + lr8;
            const unsigned short* gp = A + (size_t)(bm + row) * K + k0 + gchunk * 8;
            __builtin_amdgcn_global_load_lds(
                (const __attribute__((address_space(1))) void*)gp,
                (__attribute__((address_space(3))) void*)&As[cs * 512], 16, 0, 0);
        }
        #pragma unroll
        for (int r = 0; r < NT / 32; ++r) {
            int cs = r * 4 + wave;
            int row = cs * 8 + lr8;
            const unsigned short* gp = Bt + (size_t)(bn + row) * K + k0 + gchunk * 8;
            __builtin_amdgcn_global_load_lds(
                (const __attribute__((address_space(1))) void*)gp,
                (__attribute__((address_space(3))) void*)&Bs[cs * 512], 16, 0, 0);
        }
        __syncthreads();
        #pragma unroll
        for (int kh = 0; kh < 2; ++kh) {
            int q = kh * 4 + quad;
            int pos = (q ^ (row16 & 7)) * 8;
            bf16x8 af[4], bfr[NI];
            #pragma unroll
            for (int mi = 0; mi < 4; ++mi)
                af[mi] = *(const bf16x8*)&As[(wr * 64 + mi * 16 + row16) * 64 + pos];
            #pragma unroll
            for (int ni = 0; ni < NI; ++ni)
                bfr[ni] = *(const bf16x8*)&Bs[(wc * (NT / 2) + ni * 16 + row16) * 64 + pos];
            #pragma unroll
            for (int mi = 0; mi < 4; ++mi)
                #pragma unroll
                for (int ni = 0; ni < NI; ++ni)
                    acc[mi][ni] = __builtin_amdgcn_mfma_f32_16x16x32_bf16(
                        af[mi], bfr[ni], acc[mi][ni], 0, 0, 0);
        }
        __syncthreads();
    }

    int rbase = bm + wr * 64 + (lane >> 4) * 4;
    int cbase = bn + wc * (NT / 2) + (lane & 15);
    #pragma unroll
    for (int mi = 0; mi < 4; ++mi)
        #pragma unroll
        for (int ni = 0; ni < NI; ++ni)
            #pragma unroll
            for (int r = 0; r < 4; ++r)
                C[zoff + (size_t)(rbase + mi * 16 + r) * N + cbase + ni * 16] =
                    f2bf(acc[mi][ni][r]);
}

// ---------------------------------------------------------------------------
// Fused split-K reduce + attention halves, layer 2 (4 slices, N=448, H=8).
// ---------------------------------------------------------------------------
__global__ __launch_bounds__(256) void reduce_attn_l2(const unsigned int* __restrict__ P,
                                                      unsigned int* __restrict__ h2out,
                                                      const float* __restrict__ as2,
                                                      const float* __restrict__ ad2,
                                                      float* __restrict__ e_src,
                                                      float* __restrict__ e_dst, int M) {
    const size_t stride = (size_t)MPAD * 224;
    int wave = threadIdx.x >> 6, lane = threadIdx.x & 63;
    int node = blockIdx.x * 4 + wave;
    if (node >= M) return;
    bool act = lane < 56;
    int head = lane / 7;
    int m = lane - head * 7;
    size_t base = (size_t)node * 224 + lane * 4;
    float lo[4], hi[4];
    #pragma unroll
    for (int d = 0; d < 4; ++d) {
        float l = 0.f, hh = 0.f;
        #pragma unroll
        for (int s = 0; s < 4; ++s) {
            unsigned int v = P[s * stride + base + d];
            l  += bf2f((unsigned short)(v & 0xffffu));
            hh += bf2f((unsigned short)(v >> 16));
        }
        lo[d] = l; hi[d] = hh;
    }
    if (act) {
        #pragma unroll
        for (int d = 0; d < 4; ++d)
            h2out[base + d] = (unsigned int)f2bf(lo[d]) |
                              ((unsigned int)f2bf(hi[d]) << 16);
    }
    float ps = 0.f, pd = 0.f;
    if (act) {
        const float* as = as2 + head * 56 + m * 8;
        const float* ad = ad2 + head * 56 + m * 8;
        #pragma unroll
        for (int d = 0; d < 4; ++d) {
            ps += lo[d] * as[2 * d] + hi[d] * as[2 * d + 1];
            pd += lo[d] * ad[2 * d] + hi[d] * ad[2 * d + 1];
        }
    }
    int lead = (lane / 7) * 7;
    float ts = 0.f, td = 0.f;
    #pragma unroll
    for (int jj = 0; jj < 7; ++jj) {
        int src = lead + jj; if (src > 63) src = 63;
        ts += __shfl(ps, src);
        td += __shfl(pd, src);
    }
    if (act && m == 0) {
        e_src[node * 8 + head] = ts;
        e_dst[node * 8 + head] = td;
    }
}

// Fused reduce+attn, layer 3 (2 slices, N=128, H=4). One wave per node.
__global__ __launch_bounds__(256) void reduce_attn_l3(const unsigned int* __restrict__ P,
                                                      unsigned int* __restrict__ h2out,
                                                      const float* __restrict__ as3,
                                                      const float* __restrict__ ad3,
                                                      float* __restrict__ e_src,
                                                      float* __restrict__ e_dst, int M) {
    const size_t stride = (size_t)MPAD * 64;
    int wave = threadIdx.x >> 6, lane = threadIdx.x & 63;
    int node = blockIdx.x * 4 + wave;
    if (node >= M) return;
    int head = lane >> 4;
    int cl = (lane & 15) * 2;
    size_t idx = (size_t)node * 64 + lane;
    unsigned int v0 = P[idx], v1 = P[stride + idx];
    float lo = bf2f((unsigned short)(v0 & 0xffffu)) + bf2f((unsigned short)(v1 & 0xffffu));
    float hi = bf2f((unsigned short)(v0 >> 16)) + bf2f((unsigned short)(v1 >> 16));
    h2out[idx] = (unsigned int)f2bf(lo) | ((unsigned int)f2bf(hi) << 16);
    float ps = lo * as3[head * 32 + cl] + hi * as3[head * 32 + cl + 1];
    float pd = lo * ad3[head * 32 + cl] + hi * ad3[head * 32 + cl + 1];
    #pragma unroll
    for (int off = 8; off; off >>= 1) {
        ps += __shfl_xor(ps, off);
        pd += __shfl_xor(pd, off);
    }
    if ((lane & 15) == 0) {
        e_src[node * 4 + head] = ps;
        e_dst[node * 4 + head] = pd;
    }
}

// ---------------------------------------------------------------------------
// Layer-2 (H=8, C=56) aggregation: one wave per node, 56 active lanes.
// ---------------------------------------------------------------------------
__global__ __launch_bounds__(64) void agg_l2(const unsigned short* __restrict__ h,
                                             const float* __restrict__ e_src,
                                             const float* __restrict__ e_dst,
                                             const int* __restrict__ row_ptr,
                                             const int* __restrict__ col,
                                             const float* __restrict__ bias,
                                             unsigned short* __restrict__ out) {
    const int H = 8;
    int node = blockIdx.x;
    int lane = threadIdx.x;
    bool act = lane < 56;
    int head = act ? (lane / 7) : 0;
    int cpos = act ? (lane - head * 7) : 0;
    int rs = row_ptr[node], re = row_ptr[node + 1];
    float edv = e_dst[node * H + head];

    float dn = 0.f;
    float acc0[8], acc1[8];
    #pragma unroll
    for (int k = 0; k < 8; ++k) { acc0[k] = 0.f; acc1[k] = 0.f; }
    int i = rs;
    for (; i + 1 < re; i += 2) {
        int s0 = col[i], s1 = col[i + 1];
        float es0 = e_src[s0 * H + head];
        float es1 = e_src[s1 * H + head];
        u32x4 hv0 = *(const u32x4*)(h + (size_t)s0 * 448 + head * 56 + cpos * 8);
        u32x4 hv1 = *(const u32x4*)(h + (size_t)s1 * 448 + head * 56 + cpos * 8);
        float w0 = __expf(lrelu02(es0 + edv));
        float w1 = __expf(lrelu02(es1 + edv));
        dn += w0 + w1;
        #pragma unroll
        for (int d = 0; d < 4; ++d) {
            acc0[2 * d]     += w0 * bf2f((unsigned short)(hv0[d] & 0xffffu));
            acc0[2 * d + 1] += w0 * bf2f((unsigned short)(hv0[d] >> 16));
            acc1[2 * d]     += w1 * bf2f((unsigned short)(hv1[d] & 0xffffu));
            acc1[2 * d + 1] += w1 * bf2f((unsigned short)(hv1[d] >> 16));
        }
    }
    if (i < re) {
        int s = col[i];
        float w = __expf(lrelu02(e_src[s * H + head] + edv));
        dn += w;
        u32x4 hv = *(const u32x4*)(h + (size_t)s * 448 + head * 56 + cpos * 8);
        #pragma unroll
        for (int d = 0; d < 4; ++d) {
            acc0[2 * d]     += w * bf2f((unsigned short)(hv[d] & 0xffffu));
            acc0[2 * d + 1] += w * bf2f((unsigned short)(hv[d] >> 16));
        }
    }
    float rdn = 1.f / (dn + 1e-16f);

    if (act) {
        const float* bp = bias + head * 56 + cpos * 8;
        u32x4 o;
        #pragma unroll
        for (int d = 0; d < 4; ++d) {
            float v0 = lrelu01((acc0[2 * d] + acc1[2 * d]) * rdn + bp[2 * d]);
            float v1 = lrelu01((acc0[2 * d + 1] + acc1[2 * d + 1]) * rdn + bp[2 * d + 1]);
            o[d] = (unsigned int)f2bf(v0) | ((unsigned int)f2bf(v1) << 16);
        }
        *(u32x4*)(out + (size_t)node * 448 + head * 56 + cpos * 8) = o;
    }
}

// ---------------------------------------------------------------------------
// FUSED layer-3 aggregation + layer-4 GEMM + layer-4 attn halves.
// One wave per node. Phase 1: lanes 0-15 aggregate h3 into the node's
// 128-ch x4 row (fp32, kept in LDS — no bf16 round-trip). Phase 2: 16 lanes
// compute h4 = x4·W4 from LDS (W4 transposed, +132 pad), write bf16 h4,
// reduce e4 dots. e4 written at offset 4N (disjoint from L3 e ranges).
// ---------------------------------------------------------------------------
__global__ __launch_bounds__(64) void agg3_gemm4(const unsigned short* __restrict__ h,
                                                 const float* __restrict__ e_src,
                                                 const float* __restrict__ e_dst,
                                                 const int* __restrict__ row_ptr,
                                                 const int* __restrict__ col,
                                                 const float* __restrict__ b3,
                                                 const float* __restrict__ W4,
                                                 const float* __restrict__ as4,
                                                 const float* __restrict__ ad4,
                                                 unsigned short* __restrict__ h4,
                                                 float* __restrict__ e_src4,
                                                 float* __restrict__ e_dst4) {
    __shared__ float Wt[16 * 132];       // W4 transposed, padded
    __shared__ float xrow[128];
    const int H = 4;
    int node = blockIdx.x;
    int lane = threadIdx.x;
    for (int i = lane; i < 2048; i += 64) {
        int k = i >> 4, c = i & 15;
        Wt[c * 132 + k] = W4[i];
    }

    int head = (lane >> 2) & 3;
    int cpos = lane & 3;
    int rs = row_ptr[node], re = row_ptr[node + 1];
    float edv = e_dst[node * H + head];

    float dn = 0.f;
    float acc0[8], acc1[8];
    #pragma unroll
    for (int k = 0; k < 8; ++k) { acc0[k] = 0.f; acc1[k] = 0.f; }
    int i = rs;
    for (; i + 1 < re; i += 2) {
        int s0 = col[i], s1 = col[i + 1];
        float es0 = e_src[s0 * H + head];
        float es1 = e_src[s1 * H + head];
        u32x4 hv0 = *(const u32x4*)(h + (size_t)s0 * 128 + head * 32 + cpos * 8);
        u32x4 hv1 = *(const u32x4*)(h + (size_t)s1 * 128 + head * 32 + cpos * 8);
        float w0 = __expf(lrelu02(es0 + edv));
        float w1 = __expf(lrelu02(es1 + edv));
        dn += w0 + w1;
        #pragma unroll
        for (int d = 0; d < 4; ++d) {
            acc0[2 * d]     += w0 * bf2f((unsigned short)(hv0[d] & 0xffffu));
            acc0[2 * d + 1] += w0 * bf2f((unsigned short)(hv0[d] >> 16));
            acc1[2 * d]     += w1 * bf2f((unsigned short)(hv1[d] & 0xffffu));
            acc1[2 * d + 1] += w1 * bf2f((unsigned short)(hv1[d] >> 16));
        }
    }
    if (i < re) {
        int s = col[i];
        float w = __expf(lrelu02(e_src[s * H + head] + edv));
        dn += w;
        u32x4 hv = *(const u32x4*)(h + (size_t)s * 128 + head * 32 + cpos * 8);
        #pragma unroll
        for (int d = 0; d < 4; ++d) {
            acc0[2 * d]     += w * bf2f((unsigned short)(hv[d] & 0xffffu));
            acc0[2 * d + 1] += w * bf2f((unsigned short)(hv[d] >> 16));
        }
    }
    float rdn = 1.f / (dn + 1e-16f);

    if (lane < 16) {
        int cb = head * 32 + cpos * 8;
        const float* bp = b3 + cb;
        #pragma unroll
        for (int d = 0; d < 4; ++d) {
            xrow[cb + 2 * d]     = lrelu01((acc0[2 * d] + acc1[2 * d]) * rdn + bp[2 * d]);
            xrow[cb + 2 * d + 1] = lrelu01((acc0[2 * d + 1] + acc1[2 * d + 1]) * rdn + bp[2 * d + 1]);
        }
    }
    __syncthreads();

    if (lane < 16) {
        const float* wrow = &Wt[lane * 132];
        float acc = 0.f;
        #pragma unroll
        for (int k4 = 0; k4 < 32; ++k4) {
            f32x4 xv = *(const f32x4*)&xrow[k4 * 4];
            f32x4 wv = *(const f32x4*)&wrow[k4 * 4];
            acc += xv[0] * wv[0] + xv[1] * wv[1] + xv[2] * wv[2] + xv[3] * wv[3];
        }
        h4[(size_t)node * 16 + lane] = f2bf(acc);
        float vs = acc * as4[lane];
        float vd = acc * ad4[lane];
        #pragma unroll
        for (int off = 1; off < 16; off <<= 1) {
            vs += __shfl_xor(vs, off);
            vd += __shfl_xor(vd, off);
        }
        if (lane == 0) { e_src4[node] = vs; e_dst4[node] = vd; }
    }
}

// Layer-4 fused: aggregate (H=1, C=16) + bias + LeakyReLU(0.1) + row softmax.
__global__ __launch_bounds__(64) void agg4_softmax(const unsigned int* __restrict__ h2,
                                                   const float* __restrict__ e_src,
                                                   const float* __restrict__ e_dst,
                                                   const int* __restrict__ row_ptr,
                                                   const int* __restrict__ col,
                                                   const float* __restrict__ bias,
                                                   float* __restrict__ out) {
    int node = blockIdx.x;
    int lane = threadIdx.x;
    int cpos = lane & 7;
    int rs = row_ptr[node], re = row_ptr[node + 1];
    float edv = e_dst[node];

    float dn = 0.f, a0 = 0.f, a1 = 0.f;
    for (int i = rs; i < re; ++i) {
        int s = col[i];
        float w = __expf(lrelu02(e_src[s] + edv));
        dn += w;
        unsigned int hv = h2[(size_t)s * 8 + cpos];
        a0 += w * bf2f((unsigned short)(hv & 0xffffu));
        a1 += w * bf2f((unsigned short)(hv >> 16));
    }
    float rdn = 1.f / (dn + 1e-16f);
    float v0 = lrelu01(a0 * rdn + bias[2 * cpos]);
    float v1 = lrelu01(a1 * rdn + bias[2 * cpos + 1]);

    float m = fmaxf(v0, v1);
    #pragma unroll
    for (int off = 4; off; off >>= 1) m = fmaxf(m, __shfl_xor(m, off));
    float e0 = __expf(v0 - m), e1 = __expf(v1 - m);
    float s = e0 + e1;
    #pragma unroll
    for (int off = 4; off; off >>= 1) s += __shfl_xor(s, off);
    float r = 1.f / s;
    if (lane < 8) {
        out[node * 16 + 2 * cpos]     = e0 * r;
        out[node * 16 + 2 * cpos + 1] = e1 * r;
    }
}

// ---------------------------------------------------------------------------
extern "C" void kernel_launch(void* const* d_in, const int* in_sizes, int n_in,
                              void* d_out, int out_size, void* d_ws, size_t ws_size,
                              hipStream_t stream) {
    const float* x   = (const float*)d_in[0];
    const int*   ei  = (const int*)d_in[1];
    const float* W1  = (const float*)d_in[2];
    const float* as1 = (const float*)d_in[3];
    const float* ad1 = (const float*)d_in[4];
    const float* b1  = (const float*)d_in[5];
    const float* W2  = (const float*)d_in[6];
    const float* as2 = (const float*)d_in[7];
    const float* ad2 = (const float*)d_in[8];
    const float* b2  = (const float*)d_in[9];
    const float* W3  = (const float*)d_in[10];
    const float* as3 = (const float*)d_in[11];
    const float* ad3 = (const float*)d_in[12];
    const float* b3  = (const float*)d_in[13];
    const float* W4  = (const float*)d_in[14];
    const float* as4 = (const float*)d_in[15];
    const float* ad4 = (const float*)d_in[16];
    const float* b4  = (const float*)d_in[17];

    char* ws = (char*)d_ws;
    size_t off = 0;
    auto alloc = [&](size_t bytes) -> void* {
        void* p = ws + off;
        off = (off + bytes + 255) & ~(size_t)255;
        return p;
    };
    unsigned short* hbuf = (unsigned short*)alloc((size_t)MPAD * 2560 * sizeof(short));
    unsigned short* abuf = (unsigned short*)alloc((size_t)MPAD * 2560 * sizeof(short));
    unsigned short* pbuf = (unsigned short*)alloc((size_t)4 * MPAD * 448 * sizeof(short));
    unsigned short* xagg = (unsigned short*)alloc((size_t)MPAD * 10 * 128 * sizeof(short));
    unsigned short* W1t  = (unsigned short*)alloc((size_t)2560 * 128 * sizeof(short));
    unsigned short* W2t  = (unsigned short*)alloc((size_t)448 * 2560 * sizeof(short));
    unsigned short* W3t  = (unsigned short*)alloc((size_t)128 * 448 * sizeof(short));
    float* wsrc   = (float*)alloc((size_t)10 * 128 * sizeof(float));
    float* wdst   = (float*)alloc((size_t)10 * 128 * sizeof(float));
    float* e_src  = (float*)alloc((size_t)NNODES * 10 * sizeof(float));
    float* e_dst  = (float*)alloc((size_t)NNODES * 10 * sizeof(float));
    int* indeg    = (int*)alloc(NNODES * sizeof(int));
    int* row_ptr  = (int*)alloc((NNODES + 1) * sizeof(int));
    int* cursor   = (int*)alloc(NNODES * sizeof(int));
    int* col      = (int*)alloc(ETOT * sizeof(int));
    (void)ws_size;

    hipMemsetAsync(indeg, 0, NNODES * sizeof(int), stream);

    prep_all<<<352 + 5000 + 5 + 1496, 256, 0, stream>>>(
        ei, indeg, x, abuf, W1, as1, ad1, wsrc, wdst, W2, W3, W1t, W2t, W3t);
    scan_rowptr<<<1, 1024, 0, stream>>>(indeg, row_ptr, cursor, NNODES);
    scatter_e1<<<352 + 2500, 256, 0, stream>>>(
        ei, cursor, col, abuf, wsrc, wdst, e_src, e_dst);

    const int Mb = MPAD / GBM;   // 79

    // ---- Layer 1 (linearity-restructured): agg_x -> batched GEMM ----
    agg_x<<<NNODES, 64, 0, stream>>>(abuf, e_src, e_dst, row_ptr, col, xagg);
    gemm_l1<<<dim3(20, Mb), 256, 0, stream>>>(xagg, W1t, b1, abuf);   // abuf = x2

    // ---- Layer 2: 2560 -> 8x56 (GBK=64, XCD-swizzled, split-K=4) ----
    gemm_k64<64><<<dim3(8 * 7 * 10, 4), 256, 0, stream>>>(
        abuf, W2t, pbuf, 448, 7, 2560, 640);
    reduce_attn_l2<<<2500, 256, 0, stream>>>(
        (const unsigned int*)pbuf, (unsigned int*)hbuf, as2, ad2, e_src, e_dst, NNODES);
    agg_l2<<<NNODES, 64, 0, stream>>>(hbuf, e_src, e_dst, row_ptr, col, b2, abuf);

    // ---- Layer 3: 448 -> 4x32 (GBK=64, XCD-swizzled, split-K=2: 256+192) ----
    gemm_k64<64><<<dim3(8 * 2 * 10, 2), 256, 0, stream>>>(
        abuf, W3t, pbuf, 128, 2, 448, 256);
    reduce_attn_l3<<<2500, 256, 0, stream>>>(
        (const unsigned int*)pbuf, (unsigned int*)hbuf, as3, ad3, e_src, e_dst, NNODES);

    // ---- Fused: layer-3 aggregation + layer-4 GEMM + layer-4 attn ----
    agg3_gemm4<<<NNODES, 64, 0, stream>>>(
        hbuf, e_src, e_dst, row_ptr, col, b3, W4, as4, ad4,
        abuf, e_src + (size_t)NNODES * 4, e_dst + (size_t)NNODES * 4);

    // ---- Layer-4 aggregation + bias + lrelu + softmax ----
    agg4_softmax<<<NNODES, 64, 0, stream>>>(
        (const unsigned int*)abuf, e_src + (size_t)NNODES * 4,
        e_dst + (size_t)NNODES * 4, row_ptr, col, b4, (float*)d_out);
}